// Round 8
// baseline (163.826 us; speedup 1.0000x reference)
//
#include <hip/hip_runtime.h>
#include <hip/hip_bf16.h>

#define HH 64
#define WW 64
#define CIN 128
#define COUT 256
#define KK 1152            // CIN*9
#define PW 66              // padded NHWC width/height
#define XTIMG (PW*PW*CIN)  // elems per padded image = 557568

typedef short bf16x8 __attribute__((ext_vector_type(8)));
typedef float f32x4  __attribute__((ext_vector_type(4)));

__device__ inline short f2bf(float f) {
    union { float f; unsigned u; } v; v.f = f;
    unsigned r = v.u + 0x7FFFu + ((v.u >> 16) & 1u);   // RNE
    return (short)(r >> 16);
}
__device__ inline float lo16(unsigned u) {
    union { unsigned u; float f; } v; v.u = u << 16; return v.f;
}
__device__ inline float hi16(unsigned u) {
    union { unsigned u; float f; } v; v.u = u & 0xffff0000u; return v.f;
}
__device__ inline unsigned pk2(float lo, float hi) {
    union { __hip_bfloat162 h; unsigned u; } c;
    c.h = __float22bfloat162_rn(make_float2(lo, hi));
    return c.u;
}

// ---- kernel 0: prep. blocks 0..527: NCHW f32 -> NHWC bf16 padded transpose (LDS-free).
//                blocks 528..689: weight casts to MFMA A-fragment order.
__global__ __launch_bounds__(256) void prep(const float* __restrict__ x,
                                            const float* __restrict__ wd,
                                            const float* __restrict__ wo,
                                            ushort* __restrict__ xt,
                                            short* __restrict__ wf,
                                            short* __restrict__ wfo) {
    int bi = blockIdx.x, t = threadIdx.x;
    if (bi < 528) {
        int b = bi & 7, hp = bi >> 3;                    // XCD-pinned by image
        ushort* row = xt + ((size_t)b * PW + hp) * PW * CIN;   // 8448 elems
        if (hp == 0 || hp == 65) {
            uint4 z = {0, 0, 0, 0};
            for (int f = t; f < 1056; f += 256) ((uint4*)row)[f] = z;
            return;
        }
        int h = hp - 1;
        int w = t & 63, c0 = (t >> 6) * 32;
        const float* xs = x + (((size_t)b * CIN + c0) << 12) + (h << 6) + w;
        float v[32];
#pragma unroll
        for (int i = 0; i < 32; i++) v[i] = xs[(size_t)i << 12];   // coalesced dwords
        unsigned dw[16];
#pragma unroll
        for (int i = 0; i < 16; i++) dw[i] = pk2(v[2 * i], v[2 * i + 1]);
        ushort* dst = row + ((w + 1) * 128 + c0);
#pragma unroll
        for (int i = 0; i < 4; i++) *(uint4*)(dst + i * 8) = *(uint4*)&dw[i * 4];
        if (t < 32) {                                    // zero border cols w=0,65
            uint4 z = {0, 0, 0, 0};
            int px = (t >> 4) * 65;
            *(uint4*)(row + px * 128 + (t & 15) * 8) = z;
        }
        return;
    }
    // ---- weight cast: element ((m*36+ks)*64+l)*8+j, ck' = ks*32+(l>>4)*8+j, c=ck'&127, k=ck'>>7
    int flat = (bi - 528) * 256 + t;       // 0..41471 = 18 m * 36 ks * 64 l
    int m = flat / 2304;
    int r = flat - m * 2304;
    int ks = r >> 6, l = r & 63;
    bf16x8 v8;
    if (m < 16) {
        int co = m * 16 + (l & 15);
#pragma unroll
        for (int j = 0; j < 8; j++) {
            int ckp = ks * 32 + ((l >> 4) << 3) + j;
            int c = ckp & 127, k = ckp >> 7;
            v8[j] = f2bf(wd[(size_t)co * KK + c * 9 + k]);
        }
        *(bf16x8*)(wf + ((size_t)(m * 36 + ks) * 64 + l) * 8) = v8;
    } else {
        int mm = m - 16;
        int co = mm * 16 + (l & 15);
#pragma unroll
        for (int j = 0; j < 8; j++) {
            int ckp = ks * 32 + ((l >> 4) << 3) + j;
            int c = ckp & 127, k = ckp >> 7;
            v8[j] = (co < 18) ? f2bf(wo[(size_t)co * KK + c * 9 + k]) : (short)0;
        }
        *(bf16x8*)(wfo + ((size_t)(mm * 36 + ks) * 64 + l) * 8) = v8;
    }
}

// ---- kernel 1: FUSED offset-conv + sampling + deform MFMA. 512 threads = 8 waves.
// grid 512: b=bi&7 (XCD pin), h=bi>>3. Wave wv owns co 32*wv..32*wv+31 (2 m-tiles x 4 n-tiles).
// K-loop in super-chunks of 256 (2 kernel-points), dbuf s_val, prefetch across MFMA block.
__global__ __launch_bounds__(512, 4) void fused_deform(const ushort* __restrict__ xt,
                                                       const short* __restrict__ wf,
                                                       const short* __restrict__ wfo,
                                                       const float* __restrict__ bo,
                                                       const float* __restrict__ bias,
                                                       float* __restrict__ out) {
    // LDS union: s_off (4.5 KB) aliases s_val (dead after sampling barrier). Total 77056 B.
    __shared__ __align__(16) char smem[77056];
    short*   s_val = (short*)smem;                        // [2][64][256] = 65536 B
    float*   s_off = (float*)smem;                        // [18][64] (aliased)
    float4*  s_w   = (float4*)(smem + 65536);             // [9][64] = 9216 B
    ushort2* s_o   = (ushort2*)(smem + 65536 + 9216);     // [9][64] = 2304 B

    int t = threadIdx.x, bi = blockIdx.x;
    int b = bi & 7, h = bi >> 3;
    const ushort* xb = xt + (size_t)b * XTIMG;
    int wv = t >> 6, l = t & 63, lane16 = l & 15, quad = l >> 4;

    // ========== phase 0: offset conv (M=32 pad of 18, K=1152), LDS-free ==========
    {
        int mt = wv >> 2, nt = wv & 3;
        int pix0 = nt * 16 + lane16;
        f32x4 aoff = {0.f, 0.f, 0.f, 0.f};
        const short* A = wfo + (size_t)mt * 36 * 512 + l * 8;
#pragma unroll
        for (int k = 0; k < 9; k++) {
            const ushort* bbase = xb + ((size_t)(h + k / 3) * PW + pix0 + k % 3) * CIN + quad * 8;
#pragma unroll
            for (int ksp = 0; ksp < 4; ksp++) {
                bf16x8 bfr = *(const bf16x8*)(bbase + ksp * 32);
                bf16x8 afr = *(const bf16x8*)(A + (k * 4 + ksp) * 512);
                aoff = __builtin_amdgcn_mfma_f32_16x16x32_bf16(afr, bfr, aoff, 0, 0, 0);
            }
        }
#pragma unroll
        for (int r = 0; r < 4; r++) {
            int co = mt * 16 + quad * 4 + r;
            if (co < 18) s_off[co * 64 + pix0] = aoff[r] + bo[co];
        }
    }
    __syncthreads();

    // ========== sampling params: 9 kernel points x 64 pixels ==========
    for (int jj = t; jj < 576; jj += 512) {
        int k = jj >> 6, pixj = jj & 63;
        float dy = s_off[(2 * k) * 64 + pixj];
        float dx = s_off[(2 * k + 1) * 64 + pixj];
        float py = (float)(h + k / 3 - 1) + dy;
        float px = (float)(pixj + k % 3 - 1) + dx;
        float y0f = floorf(py), x0f = floorf(px);
        float ly = py - y0f, lx = px - x0f;
        int y0 = (int)y0f, x0 = (int)x0f;
        float a0, a1;
        if (x0 >= 0 && x0 <= 62)      { a0 = 1.f - lx; a1 = lx; }
        else if (x0 == -1)            { a0 = lx;       a1 = 0.f; }
        else if (x0 == 63)            { a0 = 0.f;      a1 = 1.f - lx; }
        else                          { a0 = 0.f;      a1 = 0.f; }
        int xb0 = min(max(x0, 0), 62);
        bool vy0 = (y0 >= 0) && (y0 < HH);
        bool vy1 = (y0 >= -1) && (y0 < HH - 1);
        int y0c = min(max(y0, 0), HH - 1);
        int y1c = min(max(y0 + 1, 0), HH - 1);
        float wy0 = (1.f - ly) * (vy0 ? 1.f : 0.f);
        float wy1 = ly * (vy1 ? 1.f : 0.f);
        s_o[k * 64 + pixj] = make_ushort2((ushort)((y0c + 1) * PW + xb0 + 1),
                                          (ushort)((y1c + 1) * PW + xb0 + 1));
        s_w[k * 64 + pixj] = make_float4(wy0 * a0, wy0 * a1, wy1 * a0, wy1 * a1);
    }

    // ========== main loop ==========
    int p = t >> 3, j = t & 7, pm = p & 15, jj8 = j * 8;   // 8 threads/pixel
    bf16x8 rv[16];                                         // 2 k-points in flight

    auto gld = [&](int k, bf16x8* r) {                     // 8x 16B, 128B-coalesced per pixel
        ushort2 o = s_o[k * 64 + p];
        const ushort* q0 = xb + (size_t)o.x * CIN + jj8;
        const ushort* q1 = xb + (size_t)o.y * CIN + jj8;
        r[0] = *(const bf16x8*)(q0);       r[1] = *(const bf16x8*)(q0 + 64);
        r[2] = *(const bf16x8*)(q0 + 128); r[3] = *(const bf16x8*)(q0 + 192);
        r[4] = *(const bf16x8*)(q1);       r[5] = *(const bf16x8*)(q1 + 64);
        r[6] = *(const bf16x8*)(q1 + 128); r[7] = *(const bf16x8*)(q1 + 192);
    };
    auto gst = [&](int k, int buf, bf16x8* r) {            // bilinear in regs, 2 conflict-free stores
        float4 w4 = s_w[k * 64 + p];
        unsigned oa[4], ob[4];
        const unsigned* cA0 = (const unsigned*)&r[0];      // c00 lo-granule
        const unsigned* cA1 = (const unsigned*)&r[2];      // c01
        const unsigned* cA2 = (const unsigned*)&r[4];      // c10
        const unsigned* cA3 = (const unsigned*)&r[6];      // c11
        const unsigned* cB0 = (const unsigned*)&r[1];      // hi-granule (+64 ch)
        const unsigned* cB1 = (const unsigned*)&r[3];
        const unsigned* cB2 = (const unsigned*)&r[5];
        const unsigned* cB3 = (const unsigned*)&r[7];
#pragma unroll
        for (int d = 0; d < 4; d++) {
            float vl = w4.x * lo16(cA0[d]) + w4.y * lo16(cA1[d]) + w4.z * lo16(cA2[d]) + w4.w * lo16(cA3[d]);
            float vh = w4.x * hi16(cA0[d]) + w4.y * hi16(cA1[d]) + w4.z * hi16(cA2[d]) + w4.w * hi16(cA3[d]);
            oa[d] = pk2(vl, vh);
            float ul = w4.x * lo16(cB0[d]) + w4.y * lo16(cB1[d]) + w4.z * lo16(cB2[d]) + w4.w * lo16(cB3[d]);
            float uh = w4.x * hi16(cB0[d]) + w4.y * hi16(cB1[d]) + w4.z * hi16(cB2[d]) + w4.w * hi16(cB3[d]);
            ob[d] = pk2(ul, uh);
        }
        short* base = s_val + buf * 16384 + p * 256 + (k & 1) * 128;
        *(bf16x8*)(base + ((j    ) ^ pm) * 8) = *(bf16x8*)oa;   // granule j
        *(bf16x8*)(base + ((j + 8) ^ pm) * 8) = *(bf16x8*)ob;   // granule j+8
    };

    f32x4 z = {0.f, 0.f, 0.f, 0.f};
    f32x4 acc[2][4];
#pragma unroll
    for (int i = 0; i < 2; i++)
#pragma unroll
        for (int q2 = 0; q2 < 4; q2++) acc[i][q2] = z;
    const short* Aw = wf + (size_t)l * 8 + (size_t)(wv * 2) * 36 * 512;

    __syncthreads();                                 // s_o/s_w ready; s_off dead
    gld(0, rv); gld(1, rv + 8);
    gst(0, 0, rv); gst(1, 0, rv + 8);
    __syncthreads();                                 // buf0 ready

#pragma unroll 1
    for (int s = 0; s < 5; s++) {
        int kn = 2 * s + 2;
        if (kn <= 8) gld(kn, rv);                    // prefetch: in flight across MFMA block
        if (kn + 1 <= 8) gld(kn + 1, rv + 8);
        const short* sv = s_val + (s & 1) * 16384;
        int nk = (s == 4) ? 4 : 8;
#pragma unroll 4
        for (int ksp = 0; ksp < nk; ksp++) {
            int ks = s * 8 + ksp;
            int colg = (((ksp & 3) * 4 + quad) ^ lane16) * 8 + (ksp >> 2) * 128;
            bf16x8 b0 = *(const bf16x8*)(sv + (lane16     ) * 256 + colg);
            bf16x8 b1 = *(const bf16x8*)(sv + (lane16 + 16) * 256 + colg);
            bf16x8 b2 = *(const bf16x8*)(sv + (lane16 + 32) * 256 + colg);
            bf16x8 b3 = *(const bf16x8*)(sv + (lane16 + 48) * 256 + colg);
            bf16x8 a0 = *(const bf16x8*)(Aw + (size_t)(0 * 36 + ks) * 512);
            bf16x8 a1 = *(const bf16x8*)(Aw + (size_t)(1 * 36 + ks) * 512);
            acc[0][0] = __builtin_amdgcn_mfma_f32_16x16x32_bf16(a0, b0, acc[0][0], 0, 0, 0);
            acc[0][1] = __builtin_amdgcn_mfma_f32_16x16x32_bf16(a0, b1, acc[0][1], 0, 0, 0);
            acc[0][2] = __builtin_amdgcn_mfma_f32_16x16x32_bf16(a0, b2, acc[0][2], 0, 0, 0);
            acc[0][3] = __builtin_amdgcn_mfma_f32_16x16x32_bf16(a0, b3, acc[0][3], 0, 0, 0);
            acc[1][0] = __builtin_amdgcn_mfma_f32_16x16x32_bf16(a1, b0, acc[1][0], 0, 0, 0);
            acc[1][1] = __builtin_amdgcn_mfma_f32_16x16x32_bf16(a1, b1, acc[1][1], 0, 0, 0);
            acc[1][2] = __builtin_amdgcn_mfma_f32_16x16x32_bf16(a1, b2, acc[1][2], 0, 0, 0);
            acc[1][3] = __builtin_amdgcn_mfma_f32_16x16x32_bf16(a1, b3, acc[1][3], 0, 0, 0);
        }
        if (kn <= 8) gst(kn, (s + 1) & 1, rv);
        if (kn + 1 <= 8) gst(kn + 1, (s + 1) & 1, rv + 8);
        if (s < 4) __syncthreads();
    }

    // ---- epilogue: bias + relu + store. D: col(pix)=lane16, row(co)=quad*4+r
#pragma unroll
    for (int mt2 = 0; mt2 < 2; mt2++) {
        int co = (wv * 2 + mt2) * 16 + quad * 4;
#pragma unroll
        for (int nt = 0; nt < 4; nt++) {
            int colx = nt * 16 + lane16;
#pragma unroll
            for (int rr = 0; rr < 4; rr++) {
                float v = acc[mt2][nt][rr] + bias[co + rr];
                out[(((size_t)b * COUT + co + rr) << 12) + (h << 6) + colx] = fmaxf(v, 0.f);
            }
        }
    }
}

extern "C" void kernel_launch(void* const* d_in, const int* in_sizes, int n_in,
                              void* d_out, int out_size, void* d_ws, size_t ws_size,
                              hipStream_t stream) {
    const float* x     = (const float*)d_in[0];
    const float* w_off = (const float*)d_in[1];
    const float* b_off = (const float*)d_in[2];
    const float* w_def = (const float*)d_in[3];
    const float* b_def = (const float*)d_in[4];
    float* out = (float*)d_out;

    // ws: wf bf16 [16*36*512] | wfo bf16 [2*36*512] | xt bf16 [8*66*66*128]
    short*  wf  = (short*)d_ws;
    short*  wfo = wf + (size_t)16 * 36 * 512;
    ushort* xt  = (ushort*)(wfo + (size_t)2 * 36 * 512);

    prep<<<690, 256, 0, stream>>>(x, w_def, w_off, xt, wf, wfo);
    fused_deform<<<512, 512, 0, stream>>>(xt, wf, wfo, b_off, b_def, out);
}

// Round 9
// 130.543 us; speedup vs baseline: 1.2550x; 1.2550x over previous
//
#include <hip/hip_runtime.h>
#include <hip/hip_bf16.h>

#define HH 64
#define WW 64
#define CIN 128
#define COUT 256
#define KK 1152            // CIN*9
#define PW 66              // padded NHWC width/height
#define XTIMG (PW*PW*CIN)  // elems per padded image = 557568

typedef short bf16x8 __attribute__((ext_vector_type(8)));
typedef float f32x4  __attribute__((ext_vector_type(4)));

__device__ inline short f2bf(float f) {
    union { float f; unsigned u; } v; v.f = f;
    unsigned r = v.u + 0x7FFFu + ((v.u >> 16) & 1u);   // RNE
    return (short)(r >> 16);
}
__device__ inline float lo16(unsigned u) {
    union { unsigned u; float f; } v; v.u = u << 16; return v.f;
}
__device__ inline float hi16(unsigned u) {
    union { unsigned u; float f; } v; v.u = u & 0xffff0000u; return v.f;
}
__device__ inline unsigned pk2(float lo, float hi) {
    union { __hip_bfloat162 h; unsigned u; } c;
    c.h = __float22bfloat162_rn(make_float2(lo, hi));
    return c.u;
}

// ---- kernel 0: prep. blocks 0..527: NCHW f32 -> NHWC bf16 padded transpose,
//                LDS-tiled, coalesced both sides. blocks 528..689: weight casts.
__global__ __launch_bounds__(256) void prep(const float* __restrict__ x,
                                            const float* __restrict__ wd,
                                            const float* __restrict__ wo,
                                            ushort* __restrict__ xt,
                                            short* __restrict__ wf,
                                            short* __restrict__ wfo) {
    int bi = blockIdx.x, t = threadIdx.x;
    if (bi < 528) {
        int b = bi & 7, hp = bi >> 3;                    // XCD-pinned by image
        ushort* row = xt + ((size_t)b * PW + hp) * PW * CIN;   // 8448 elems
        if (hp == 0 || hp == 65) {
            uint4 z = {0, 0, 0, 0};
            for (int f = t; f < 1056; f += 256) ((uint4*)row)[f] = z;
            return;
        }
        __shared__ short tl[64 * 130];                   // [w][c], stride 130 (2-way max)
        int h = hp - 1;
        int w = t & 63, cq = t >> 6;                     // cq 0..3 -> 32 channels each
        const float* xs = x + (((size_t)b * CIN + cq * 32) << 12) + (h << 6) + w;
        short* td = &tl[w * 130 + cq * 32];
#pragma unroll
        for (int i = 0; i < 16; i++) {
            float v0 = xs[(size_t)(2 * i) << 12];        // 256B-coalesced across lanes
            float v1 = xs[(size_t)(2 * i + 1) << 12];
            *(unsigned*)(td + 2 * i) = pk2(v0, v1);      // ds_write_b32, 2-way max
        }
        __syncthreads();
#pragma unroll
        for (int pass = 0; pass < 4; pass++) {           // 1024 granules of 8 shorts
            int f = pass * 256 + t;
            int px = f >> 4, gch = (f & 15) * 8;
            bf16x8 v = *(const bf16x8*)&tl[px * 130 + gch];
            *(bf16x8*)(row + 128 + f * 8) = v;           // 4KB contiguous per instr
        }
        if (t < 32) {                                    // zero border cols w=0,65
            uint4 z = {0, 0, 0, 0};
            int px = (t >> 4) * 65;
            *(uint4*)(row + px * 128 + (t & 15) * 8) = z;
        }
        return;
    }
    // ---- weight cast: element ((m*36+ks)*64+l)*8+j, ck' = ks*32+(l>>4)*8+j, c=ck'&127, k=ck'>>7
    int flat = (bi - 528) * 256 + t;       // 0..41471 = 18 m * 36 ks * 64 l
    int m = flat / 2304;
    int r = flat - m * 2304;
    int ks = r >> 6, l = r & 63;
    bf16x8 v8;
    if (m < 16) {
        int co = m * 16 + (l & 15);
#pragma unroll
        for (int j = 0; j < 8; j++) {
            int ckp = ks * 32 + ((l >> 4) << 3) + j;
            int c = ckp & 127, k = ckp >> 7;
            v8[j] = f2bf(wd[(size_t)co * KK + c * 9 + k]);
        }
        *(bf16x8*)(wf + ((size_t)(m * 36 + ks) * 64 + l) * 8) = v8;
    } else {
        int mm = m - 16;
        int co = mm * 16 + (l & 15);
#pragma unroll
        for (int j = 0; j < 8; j++) {
            int ckp = ks * 32 + ((l >> 4) << 3) + j;
            int c = ckp & 127, k = ckp >> 7;
            v8[j] = (co < 18) ? f2bf(wo[(size_t)co * KK + c * 9 + k]) : (short)0;
        }
        *(bf16x8*)(wfo + ((size_t)(mm * 36 + ks) * 64 + l) * 8) = v8;
    }
}

// ---- kernel 1: FUSED offset-conv + sampling + deform MFMA. 512 threads = 8 waves.
// grid 512: b=bi&7 (XCD pin), h=bi>>3. Wave wv owns co 32*wv..32*wv+31.
// Super-chunks of 2 k-points, dbuf s_val, SINGLE rv[8] in flight (no spill).
__global__ __launch_bounds__(512, 4) void fused_deform(const ushort* __restrict__ xt,
                                                       const short* __restrict__ wf,
                                                       const short* __restrict__ wfo,
                                                       const float* __restrict__ bo,
                                                       const float* __restrict__ bias,
                                                       float* __restrict__ out) {
    // LDS union: s_off (4.5 KB) aliases s_val (dead after sampling barrier). Total 77056 B.
    __shared__ __align__(16) char smem[77056];
    short*   s_val = (short*)smem;                        // [2][64][256] = 65536 B
    float*   s_off = (float*)smem;                        // [18][64] (aliased)
    float4*  s_w   = (float4*)(smem + 65536);             // [9][64] = 9216 B
    ushort2* s_o   = (ushort2*)(smem + 65536 + 9216);     // [9][64] = 2304 B

    int t = threadIdx.x, bi = blockIdx.x;
    int b = bi & 7, h = bi >> 3;
    const ushort* xb = xt + (size_t)b * XTIMG;
    int wv = t >> 6, l = t & 63, lane16 = l & 15, quad = l >> 4;

    // ========== phase 0: offset conv (M=32 pad of 18, K=1152), LDS-free ==========
    {
        int mt = wv >> 2, nt = wv & 3;
        int pix0 = nt * 16 + lane16;
        f32x4 aoff = {0.f, 0.f, 0.f, 0.f};
        const short* A = wfo + (size_t)mt * 36 * 512 + l * 8;
#pragma unroll
        for (int k = 0; k < 9; k++) {
            const ushort* bbase = xb + ((size_t)(h + k / 3) * PW + pix0 + k % 3) * CIN + quad * 8;
#pragma unroll
            for (int ksp = 0; ksp < 4; ksp++) {
                bf16x8 bfr = *(const bf16x8*)(bbase + ksp * 32);
                bf16x8 afr = *(const bf16x8*)(A + (k * 4 + ksp) * 512);
                aoff = __builtin_amdgcn_mfma_f32_16x16x32_bf16(afr, bfr, aoff, 0, 0, 0);
            }
        }
#pragma unroll
        for (int r = 0; r < 4; r++) {
            int co = mt * 16 + quad * 4 + r;
            if (co < 18) s_off[co * 64 + pix0] = aoff[r] + bo[co];
        }
    }
    __syncthreads();

    // ========== sampling params: 9 kernel points x 64 pixels ==========
    for (int jj = t; jj < 576; jj += 512) {
        int k = jj >> 6, pixj = jj & 63;
        float dy = s_off[(2 * k) * 64 + pixj];
        float dx = s_off[(2 * k + 1) * 64 + pixj];
        float py = (float)(h + k / 3 - 1) + dy;
        float px = (float)(pixj + k % 3 - 1) + dx;
        float y0f = floorf(py), x0f = floorf(px);
        float ly = py - y0f, lx = px - x0f;
        int y0 = (int)y0f, x0 = (int)x0f;
        float a0, a1;
        if (x0 >= 0 && x0 <= 62)      { a0 = 1.f - lx; a1 = lx; }
        else if (x0 == -1)            { a0 = lx;       a1 = 0.f; }
        else if (x0 == 63)            { a0 = 0.f;      a1 = 1.f - lx; }
        else                          { a0 = 0.f;      a1 = 0.f; }
        int xb0 = min(max(x0, 0), 62);
        bool vy0 = (y0 >= 0) && (y0 < HH);
        bool vy1 = (y0 >= -1) && (y0 < HH - 1);
        int y0c = min(max(y0, 0), HH - 1);
        int y1c = min(max(y0 + 1, 0), HH - 1);
        float wy0 = (1.f - ly) * (vy0 ? 1.f : 0.f);
        float wy1 = ly * (vy1 ? 1.f : 0.f);
        s_o[k * 64 + pixj] = make_ushort2((ushort)((y0c + 1) * PW + xb0 + 1),
                                          (ushort)((y1c + 1) * PW + xb0 + 1));
        s_w[k * 64 + pixj] = make_float4(wy0 * a0, wy0 * a1, wy1 * a0, wy1 * a1);
    }

    // ========== main loop ==========
    int p = t >> 3, j = t & 7, pm = p & 15, jj8 = j * 8;   // 8 threads/pixel
    bf16x8 rv[8];                                          // ONE k-point in flight

    auto gld = [&](int k) {                                // 8x 16B, 128B-coalesced per pixel
        ushort2 o = s_o[k * 64 + p];
        const ushort* q0 = xb + (size_t)o.x * CIN + jj8;
        const ushort* q1 = xb + (size_t)o.y * CIN + jj8;
        rv[0] = *(const bf16x8*)(q0);       rv[1] = *(const bf16x8*)(q0 + 64);
        rv[2] = *(const bf16x8*)(q0 + 128); rv[3] = *(const bf16x8*)(q0 + 192);
        rv[4] = *(const bf16x8*)(q1);       rv[5] = *(const bf16x8*)(q1 + 64);
        rv[6] = *(const bf16x8*)(q1 + 128); rv[7] = *(const bf16x8*)(q1 + 192);
    };
    auto gst = [&](int k, int buf) {                       // bilinear in regs, conflict-free stores
        float4 w4 = s_w[k * 64 + p];
        unsigned oa[4], ob[4];
        const unsigned* cA0 = (const unsigned*)&rv[0];
        const unsigned* cA1 = (const unsigned*)&rv[2];
        const unsigned* cA2 = (const unsigned*)&rv[4];
        const unsigned* cA3 = (const unsigned*)&rv[6];
        const unsigned* cB0 = (const unsigned*)&rv[1];
        const unsigned* cB1 = (const unsigned*)&rv[3];
        const unsigned* cB2 = (const unsigned*)&rv[5];
        const unsigned* cB3 = (const unsigned*)&rv[7];
#pragma unroll
        for (int d = 0; d < 4; d++) {
            float vl = w4.x * lo16(cA0[d]) + w4.y * lo16(cA1[d]) + w4.z * lo16(cA2[d]) + w4.w * lo16(cA3[d]);
            float vh = w4.x * hi16(cA0[d]) + w4.y * hi16(cA1[d]) + w4.z * hi16(cA2[d]) + w4.w * hi16(cA3[d]);
            oa[d] = pk2(vl, vh);
            float ul = w4.x * lo16(cB0[d]) + w4.y * lo16(cB1[d]) + w4.z * lo16(cB2[d]) + w4.w * lo16(cB3[d]);
            float uh = w4.x * hi16(cB0[d]) + w4.y * hi16(cB1[d]) + w4.z * hi16(cB2[d]) + w4.w * hi16(cB3[d]);
            ob[d] = pk2(ul, uh);
        }
        short* base = s_val + buf * 16384 + p * 256 + (k & 1) * 128;
        *(bf16x8*)(base + ((j    ) ^ pm) * 8) = *(bf16x8*)oa;   // granule j
        *(bf16x8*)(base + ((j + 8) ^ pm) * 8) = *(bf16x8*)ob;   // granule j+8
    };

    f32x4 z = {0.f, 0.f, 0.f, 0.f};
    f32x4 acc[2][4];
#pragma unroll
    for (int i = 0; i < 2; i++)
#pragma unroll
        for (int q2 = 0; q2 < 4; q2++) acc[i][q2] = z;
    const short* Aw = wf + (size_t)l * 8 + (size_t)(wv * 2) * 36 * 512;

    __syncthreads();                                 // s_o/s_w ready; s_off dead
    gld(0); gst(0, 0);
    gld(1); gst(1, 0);
    __syncthreads();                                 // buf0 ready

#pragma unroll 1
    for (int s = 0; s < 5; s++) {
        const short* sv = s_val + (s & 1) * 16384;
        int k0 = 2 * s, kn = 2 * s + 2;
        if (kn <= 8) gld(kn);                        // in flight across first MFMA half
#pragma unroll
        for (int ksp = 0; ksp < 4; ksp++) {          // k-point k0 (even -> low 128)
            int ks = k0 * 4 + ksp;
            int colg = ((ksp * 4 + quad) ^ lane16) * 8;
            bf16x8 b0 = *(const bf16x8*)(sv + (lane16     ) * 256 + colg);
            bf16x8 b1 = *(const bf16x8*)(sv + (lane16 + 16) * 256 + colg);
            bf16x8 b2 = *(const bf16x8*)(sv + (lane16 + 32) * 256 + colg);
            bf16x8 b3 = *(const bf16x8*)(sv + (lane16 + 48) * 256 + colg);
            bf16x8 a0 = *(const bf16x8*)(Aw + (size_t)(0 * 36 + ks) * 512);
            bf16x8 a1 = *(const bf16x8*)(Aw + (size_t)(1 * 36 + ks) * 512);
            acc[0][0] = __builtin_amdgcn_mfma_f32_16x16x32_bf16(a0, b0, acc[0][0], 0, 0, 0);
            acc[0][1] = __builtin_amdgcn_mfma_f32_16x16x32_bf16(a0, b1, acc[0][1], 0, 0, 0);
            acc[0][2] = __builtin_amdgcn_mfma_f32_16x16x32_bf16(a0, b2, acc[0][2], 0, 0, 0);
            acc[0][3] = __builtin_amdgcn_mfma_f32_16x16x32_bf16(a0, b3, acc[0][3], 0, 0, 0);
            acc[1][0] = __builtin_amdgcn_mfma_f32_16x16x32_bf16(a1, b0, acc[1][0], 0, 0, 0);
            acc[1][1] = __builtin_amdgcn_mfma_f32_16x16x32_bf16(a1, b1, acc[1][1], 0, 0, 0);
            acc[1][2] = __builtin_amdgcn_mfma_f32_16x16x32_bf16(a1, b2, acc[1][2], 0, 0, 0);
            acc[1][3] = __builtin_amdgcn_mfma_f32_16x16x32_bf16(a1, b3, acc[1][3], 0, 0, 0);
        }
        if (kn <= 8) gst(kn, (s + 1) & 1);
        if (kn + 1 <= 8) gld(kn + 1);                // in flight across second MFMA half
        if (s < 4) {
#pragma unroll
            for (int ksp = 0; ksp < 4; ksp++) {      // k-point k0+1 (odd -> high 128)
                int ks = (k0 + 1) * 4 + ksp;
                int colg = ((ksp * 4 + quad) ^ lane16) * 8 + 128;
                bf16x8 b0 = *(const bf16x8*)(sv + (lane16     ) * 256 + colg);
                bf16x8 b1 = *(const bf16x8*)(sv + (lane16 + 16) * 256 + colg);
                bf16x8 b2 = *(const bf16x8*)(sv + (lane16 + 32) * 256 + colg);
                bf16x8 b3 = *(const bf16x8*)(sv + (lane16 + 48) * 256 + colg);
                bf16x8 a0 = *(const bf16x8*)(Aw + (size_t)(0 * 36 + ks) * 512);
                bf16x8 a1 = *(const bf16x8*)(Aw + (size_t)(1 * 36 + ks) * 512);
                acc[0][0] = __builtin_amdgcn_mfma_f32_16x16x32_bf16(a0, b0, acc[0][0], 0, 0, 0);
                acc[0][1] = __builtin_amdgcn_mfma_f32_16x16x32_bf16(a0, b1, acc[0][1], 0, 0, 0);
                acc[0][2] = __builtin_amdgcn_mfma_f32_16x16x32_bf16(a0, b2, acc[0][2], 0, 0, 0);
                acc[0][3] = __builtin_amdgcn_mfma_f32_16x16x32_bf16(a0, b3, acc[0][3], 0, 0, 0);
                acc[1][0] = __builtin_amdgcn_mfma_f32_16x16x32_bf16(a1, b0, acc[1][0], 0, 0, 0);
                acc[1][1] = __builtin_amdgcn_mfma_f32_16x16x32_bf16(a1, b1, acc[1][1], 0, 0, 0);
                acc[1][2] = __builtin_amdgcn_mfma_f32_16x16x32_bf16(a1, b2, acc[1][2], 0, 0, 0);
                acc[1][3] = __builtin_amdgcn_mfma_f32_16x16x32_bf16(a1, b3, acc[1][3], 0, 0, 0);
            }
            if (kn + 1 <= 8) gst(kn + 1, (s + 1) & 1);
            __syncthreads();
        }
    }

    // ---- epilogue: bias + relu + store. D: col(pix)=lane16, row(co)=quad*4+r
#pragma unroll
    for (int mt2 = 0; mt2 < 2; mt2++) {
        int co = (wv * 2 + mt2) * 16 + quad * 4;
#pragma unroll
        for (int nt = 0; nt < 4; nt++) {
            int colx = nt * 16 + lane16;
#pragma unroll
            for (int rr = 0; rr < 4; rr++) {
                float v = acc[mt2][nt][rr] + bias[co + rr];
                out[(((size_t)b * COUT + co + rr) << 12) + (h << 6) + colx] = fmaxf(v, 0.f);
            }
        }
    }
}

extern "C" void kernel_launch(void* const* d_in, const int* in_sizes, int n_in,
                              void* d_out, int out_size, void* d_ws, size_t ws_size,
                              hipStream_t stream) {
    const float* x     = (const float*)d_in[0];
    const float* w_off = (const float*)d_in[1];
    const float* b_off = (const float*)d_in[2];
    const float* w_def = (const float*)d_in[3];
    const float* b_def = (const float*)d_in[4];
    float* out = (float*)d_out;

    // ws: wf bf16 [16*36*512] | wfo bf16 [2*36*512] | xt bf16 [8*66*66*128]
    short*  wf  = (short*)d_ws;
    short*  wfo = wf + (size_t)16 * 36 * 512;
    ushort* xt  = (ushort*)(wfo + (size_t)2 * 36 * 512);

    prep<<<690, 256, 0, stream>>>(x, w_def, w_off, xt, wf, wfo);
    fused_deform<<<512, 512, 0, stream>>>(xt, wf, wfo, b_off, b_def, out);
}